// Round 1
// 250.799 us; speedup vs baseline: 1.1149x; 1.1149x over previous
//
#include <hip/hip_runtime.h>
#include <math.h>

typedef _Float16 f16;
typedef _Float16 f16x8 __attribute__((ext_vector_type(8)));
typedef float f32x4 __attribute__((ext_vector_type(4)));
typedef float f32x8 __attribute__((ext_vector_type(8)));

#define AS1 __attribute__((address_space(1)))
#define AS3 __attribute__((address_space(3)))

__device__ __forceinline__ void gld_lds16(const f16* g, f16* l) {
#if defined(__has_builtin) && __has_builtin(__builtin_amdgcn_global_load_lds)
    __builtin_amdgcn_global_load_lds((const AS1 void*)g, (AS3 void*)l, 16, 0, 0);
#else
    *(uint4*)l = *(const uint4*)g;
#endif
}

// ---------------- pre-pass 1: input [128,256,20,20] f32 -> [128,20,20,256] f16 ----------
__global__ __launch_bounds__(256) void transpose_input(
    const float* __restrict__ inp, f16* __restrict__ out)
{
    const int b = blockIdx.x, c0 = blockIdx.y * 32, p0 = blockIdx.z * 32;
    const int tx = threadIdx.x, ty = threadIdx.y;   // 32 x 8
    __shared__ float t[32][33];
#pragma unroll
    for (int j = 0; j < 4; ++j) {
        int c = ty + j * 8, p = p0 + tx;
        if (p < 400) t[c][tx] = inp[((size_t)b * 256 + c0 + c) * 400 + p];
    }
    __syncthreads();
#pragma unroll
    for (int j = 0; j < 4; ++j) {
        int p = p0 + ty + j * 8;
        if (p < 400) out[((size_t)b * 400 + p) * 256 + c0 + tx] = (f16)t[tx][ty + j * 8];
    }
}

// ---------------- pre-pass 2: conv_w [n=256][cin=256][p=81] f32 -> w_t[n][p*256+cin] f16 -
__global__ __launch_bounds__(256) void permute_w(
    const float* __restrict__ cw, f16* __restrict__ w_t)
{
    const int n = blockIdx.x, t = threadIdx.x;
    __shared__ f16 buf[81 * 258];
    const float* src = cw + (size_t)n * 20736;
    for (int i = t; i < 20736; i += 256) {
        int cin = i / 81, p = i - cin * 81;
        buf[p * 258 + cin] = (f16)src[i];
    }
    __syncthreads();
    f16* dst = w_t + (size_t)n * 20736;
    for (int j = t; j < 20736; j += 256) {
        int p = j >> 8, cin = j & 255;
        dst[j] = buf[p * 258 + cin];
    }
}

// ---------------- conv as implicit-im2col MFMA GEMM, deep-pipelined -------------------
// M=4608, N=256, K = 648 chunks of 32 f16 (ordered kh,kw,cin-quarter).
// Block tile 128x256, BK=32, 4 waves (2x2), wave tile 64x128 (4x8 frags of 16x16x32,
// 32 MFMA per wave per barrier). THREE LDS buffers (72 KB -> 2 blocks/CU = 8 waves/CU),
// prefetch depth 2 with counted s_waitcnt vmcnt(6) + raw s_barrier (never drains to 0
// in the main loop). Split-K=14: grid 36x1x14 = 504 blocks = 1.97/CU, single round.
// Safety: each wave's ds_reads of tile t-1 are consumed (lgkmcnt) before its tile-t
// barrier; stage of tile t+2 (into buf[(t-1)%3]) issues after that barrier and its DMA
// lands >=900cy later; vmcnt(6)-before-barrier guarantees all waves' tile-t loads are
// resident at barrier release.
#define SPLITK 14
__global__ __launch_bounds__(256, 2) void conv_mfma(
    const f16* __restrict__ in_t,   // [128,20,20,256]
    const f16* __restrict__ w_t,    // [256,20736]
    f16* __restrict__ part)         // [14,4608,256] f16
{
    __shared__ f16 As[3][128 * 32];
    __shared__ f16 Bs[3][256 * 32];
    const int tid = threadIdx.x;
    const int lane = tid & 63, wave = tid >> 6;
    const int wm = wave >> 1, wn = wave & 1;

    // 504 blocks = 8 XCDs * 63: bijective chunk swizzle so consecutive logical
    // blocks (same kz -> shared A/B K-slice) land on the same XCD's L2.
    const int bid = blockIdx.x + 36 * blockIdx.z;
    const int wgid = (bid & 7) * 63 + (bid >> 3);
    const int m0 = (wgid % 36) * 128;
    const int kz = wgid / 36;

    // K-chunk range for this split: 648 = 14*46 + 4 (first 4 splits take 47)
    const int kc0 = kz * 46 + (kz < 4 ? kz : 4);
    const int NT  = (kz < 4) ? 47 : 46;

    // staging source offsets (pre-swizzled global source, linear LDS dest):
    // issue i covers row-pair = i*32 + (tid>>3); phys slot = tid&7, logical
    // chunk = slot ^ (pair&7); chunk>>2 = row-in-pair, chunk&3 = 8-f16 quarter.
    int srcA[2], srcB[4];
#pragma unroll
    for (int i = 0; i < 2; ++i) {
        int pairp = i * 32 + (tid >> 3);
        int chunk8 = (tid & 7) ^ (pairp & 7);
        int e = chunk8 >> 2, q4 = chunk8 & 3;
        int m = m0 + pairp * 2 + e;
        int b = m / 36, hw = m - b * 36;
        int ho = hw / 6, wo = hw - ho * 6;
        srcA[i] = ((b * 20 + 2 * ho) * 20 + 2 * wo) * 256 + q4 * 8;
    }
#pragma unroll
    for (int i = 0; i < 4; ++i) {
        int pairp = i * 32 + (tid >> 3);
        int chunk8 = (tid & 7) ^ (pairp & 7);
        int e = chunk8 >> 2, q4 = chunk8 & 3;
        int n = pairp * 2 + e;
        srcB[i] = n * 20736 + q4 * 8;
    }

    // fragment read offsets inside one tile buffer (swizzled, matches staging)
    const int row = lane & 15, quad = lane >> 4;
    int offA[4], offB[8];
#pragma unroll
    for (int mt = 0; mt < 4; ++mt) {
        int m = wm * 64 + mt * 16 + row;
        int ph8 = (((m & 1) << 2) + quad) ^ ((m >> 1) & 7);
        offA[mt] = (m >> 1) * 64 + ph8 * 8;
    }
#pragma unroll
    for (int nt = 0; nt < 8; ++nt) {
        int n = wn * 128 + nt * 16 + row;
        int ph8 = (((n & 1) << 2) + quad) ^ ((n >> 1) & 7);
        offB[nt] = (n >> 1) * 64 + ph8 * 8;
    }

    f32x4 acc[4][8] = {};

#define STAGE(T, BUF) do {                                                    \
        int kc = kc0 + (T);                                                   \
        int p = kc >> 3, cq = kc & 7;                                         \
        int kh = p / 9, kw = p - kh * 9;                                      \
        int koffA = (kh * 20 + kw) * 256 + cq * 32;                           \
        int koffB = kc * 32;                                                  \
        _Pragma("unroll")                                                     \
        for (int i = 0; i < 2; ++i)                                           \
            gld_lds16(in_t + srcA[i] + koffA, &As[BUF][i * 2048 + tid * 8]);  \
        _Pragma("unroll")                                                     \
        for (int i = 0; i < 4; ++i)                                           \
            gld_lds16(w_t + srcB[i] + koffB, &Bs[BUF][i * 2048 + tid * 8]);   \
    } while (0)

    // prologue: 2 tiles in flight (12 loads/thread outstanding)
    STAGE(0, 0);
    STAGE(1, 1);

    int buf = 0;
    for (int t = 0; t < NT; ++t) {
        // wait for THIS tile's 6 loads (leave next tile's 6 in flight), then
        // barrier so every wave's loads for tile t are resident.
        if (t + 1 < NT)
            asm volatile("s_waitcnt vmcnt(6)\n\ts_barrier" ::: "memory");
        else
            asm volatile("s_waitcnt vmcnt(0)\n\ts_barrier" ::: "memory");
        if (t + 2 < NT) {
            int bn = buf + 2; if (bn >= 3) bn -= 3;
            STAGE(t + 2, bn);
        }
        const f16* Ab = &As[buf][0];
        const f16* Bb = &Bs[buf][0];
        f16x8 af[4], bfr[8];
#pragma unroll
        for (int mt = 0; mt < 4; ++mt) af[mt] = *(const f16x8*)(Ab + offA[mt]);
#pragma unroll
        for (int nt = 0; nt < 8; ++nt) bfr[nt] = *(const f16x8*)(Bb + offB[nt]);
        __builtin_amdgcn_s_setprio(1);
#pragma unroll
        for (int mt = 0; mt < 4; ++mt)
#pragma unroll
            for (int nt = 0; nt < 8; ++nt)
                acc[mt][nt] = __builtin_amdgcn_mfma_f32_16x16x32_f16(
                    af[mt], bfr[nt], acc[mt][nt], 0, 0, 0);
        __builtin_amdgcn_s_setprio(0);
        if (++buf == 3) buf = 0;
    }
#undef STAGE

    // epilogue: f16 stores to partial buffer
    const int col = lane & 15, qr = (lane >> 4) * 4;
    f16* pb = part + (size_t)kz * 4608 * 256;
#pragma unroll
    for (int mt = 0; mt < 4; ++mt)
#pragma unroll
        for (int rg = 0; rg < 4; ++rg) {
            int m = m0 + wm * 64 + mt * 16 + qr + rg;
#pragma unroll
            for (int nt = 0; nt < 8; ++nt) {
                int n = wn * 128 + nt * 16 + col;
                pb[(size_t)m * 256 + n] = (f16)acc[mt][nt][rg];
            }
        }
}

// ---------------- split-K reduce + bias + capsule squash -> x[128,1152,8] ---------------
__global__ __launch_bounds__(256) void combine_squash(
    const f16* __restrict__ part, const float* __restrict__ bias,
    float* __restrict__ x)
{
    int idx = blockIdx.x * 256 + threadIdx.x;   // over 4608*32
    int m = idx >> 5, o = idx & 31;
    int b = m / 36, hw = m - b * 36;
    float val[8];
#pragma unroll
    for (int k = 0; k < 8; ++k) val[k] = bias[k * 32 + o];
#pragma unroll
    for (int s = 0; s < SPLITK; ++s) {
        const f16* p = part + ((size_t)s * 4608 + m) * 256 + o;
#pragma unroll
        for (int k = 0; k < 8; ++k) val[k] += (float)p[k * 32];
    }
    float sn = 0.f;
#pragma unroll
    for (int k = 0; k < 8; ++k) sn += val[k] * val[k];
    float scale = sqrtf(sn) / (1.f + sn);
    int r = o * 36 + hw;
    float* xp = x + ((size_t)b * 1152 + r) * 8;
#pragma unroll
    for (int k = 0; k < 8; ++k) xp[k] = val[k] * scale;
}

// ---------------- pred (f16) + fused routing-iter-0 s-accumulation ----------------------
// pred[c,b,r,o] = sum_k x[b,r,k]*rw[c,r,k,o]; also s0[c,b,o] += sum_r pred. s0 pre-zeroed.
__global__ __launch_bounds__(256) void pred_s0(
    const float* __restrict__ x, const float* __restrict__ rw,
    f16* __restrict__ pred, float* __restrict__ s0)
{
    const int c = blockIdx.x, r0 = blockIdx.y * 32, b0 = blockIdx.z * 32;
    const int tid = threadIdx.x;
    const int o = tid & 15, rp = tid >> 4;
    const int r = r0 + rp * 2;

    __shared__ float s_sh[32 * 16];
    s_sh[tid] = 0.f; s_sh[tid + 256] = 0.f;

    float W0[8], W1[8];
    const float* wb = rw + ((size_t)(c * 1152 + r) * 8) * 16 + o;
#pragma unroll
    for (int k = 0; k < 8; ++k) { W0[k] = wb[k * 16]; W1[k] = wb[128 + k * 16]; }
    __syncthreads();

    for (int bb = 0; bb < 32; ++bb) {
        const int b = b0 + bb;
        const float4* xp = (const float4*)(x + ((size_t)b * 1152 + r) * 8);
        float4 xa = xp[0], xb = xp[1], xc = xp[2], xd = xp[3];
        float p0 = xa.x * W0[0] + xa.y * W0[1] + xa.z * W0[2] + xa.w * W0[3]
                 + xb.x * W0[4] + xb.y * W0[5] + xb.z * W0[6] + xb.w * W0[7];
        float p1 = xc.x * W1[0] + xc.y * W1[1] + xc.z * W1[2] + xc.w * W1[3]
                 + xd.x * W1[4] + xd.y * W1[5] + xd.z * W1[6] + xd.w * W1[7];
        f16* pb = pred + ((size_t)(c * 128 + b) * 1152 + r) * 16 + o;
        pb[0]  = (f16)p0;
        pb[16] = (f16)p1;
        float ps = p0 + p1;
        ps += __shfl_xor(ps, 16);
        ps += __shfl_xor(ps, 32);
        if ((tid & 63) < 16) atomicAdd(&s_sh[bb * 16 + o], ps);
    }
    __syncthreads();
    for (int i = tid; i < 512; i += 256) {
        int bb = i >> 4, oo = i & 15;
        atomicAdd(&s0[((size_t)c * 128 + b0 + bb) * 16 + oo], s_sh[i]);
    }
}

// ---------------- routing iteration with inline batch-squash ----------------------------
__global__ __launch_bounds__(256) void route_f16(
    const f16* __restrict__ pred, const float* __restrict__ s_in,
    const float* __restrict__ z_in, const float* __restrict__ a_in,
    float* __restrict__ a_out, float* __restrict__ s_out, float* __restrict__ z_out)
{
    const int c = blockIdx.x, b = blockIdx.y, tid = threadIdx.x;
    const size_t base = (size_t)(c * 128 + b) * 1152;

    __shared__ float vs[16];
    __shared__ float mat[128][17];
    __shared__ float red[256][16];
    __shared__ float red2[16][16];
    __shared__ float zred[256];
    __shared__ float zpart[16];

    {   // inline squash(s_prev/z_prev, axis=batch) -> v_prev for this (c,b)
        if (tid < 128) {
            float zin = z_in ? 1.f / z_in[c * 128 + tid] : (1.f / 1152.f);
            const float* sp = s_in + (size_t)(c * 128 + tid) * 16;
#pragma unroll
            for (int o = 0; o < 16; ++o) mat[tid][o] = sp[o] * zin;
        }
        __syncthreads();
        if (tid < 16) {
            float sn = 0.f;
            for (int i = 0; i < 128; ++i) { float q = mat[i][tid]; sn += q * q; }
            vs[tid] = mat[b][tid] * sqrtf(sn) / (1.f + sn);
        }
        __syncthreads();
    }

    float sacc[16];
#pragma unroll
    for (int o = 0; o < 16; ++o) sacc[o] = 0.f;
    float zacc = 0.f;

    for (int r = tid; r < 1152; r += 256) {
        const f16x8* pp = (const f16x8*)(pred + (base + r) * 16);
        f32x8 q0 = __builtin_convertvector(pp[0], f32x8);
        f32x8 q1 = __builtin_convertvector(pp[1], f32x8);
        float contrib = 0.f;
#pragma unroll
        for (int j = 0; j < 8; ++j) contrib += q0[j] * vs[j] + q1[j] * vs[j + 8];
        float an = contrib + (a_in ? a_in[base + r] : 0.f);
        if (a_out) a_out[base + r] = an;
        float e = __expf(an);
#pragma unroll
        for (int j = 0; j < 8; ++j) { sacc[j] += e * q0[j]; sacc[j + 8] += e * q1[j]; }
        zacc += e;
    }

#pragma unroll
    for (int o = 0; o < 16; ++o) red[tid][o] = sacc[o];
    zred[tid] = zacc;
    __syncthreads();
    {
        const int o = tid & 15, seg = tid >> 4;
        float t = 0.f;
#pragma unroll
        for (int j = 0; j < 16; ++j) t += red[seg * 16 + j][o];
        red2[seg][o] = t;
        if (tid < 16) {
            float tz = 0.f;
#pragma unroll
            for (int j = 0; j < 16; ++j) tz += zred[tid * 16 + j];
            zpart[tid] = tz;
        }
    }
    __syncthreads();
    if (tid < 16) {
        float t = 0.f;
#pragma unroll
        for (int seg = 0; seg < 16; ++seg) t += red2[seg][tid];
        s_out[(size_t)(c * 128 + b) * 16 + tid] = t;
    } else if (tid == 16) {
        float tz = 0.f;
#pragma unroll
        for (int j = 0; j < 16; ++j) tz += zpart[j];
        z_out[c * 128 + b] = tz;
    }
}

// ---------------- final: v = squash(s/z, axis=batch) -> out[b,c,o] ----------------------
__global__ __launch_bounds__(128) void squash_final(
    const float* __restrict__ s, const float* __restrict__ z,
    float* __restrict__ out)
{
    const int c = blockIdx.x, b = threadIdx.x;   // 10 blocks, 128 threads
    float sv[16];
    const float* sp = s + ((size_t)c * 128 + b) * 16;
    float zin = 1.f / z[c * 128 + b];
#pragma unroll
    for (int o = 0; o < 16; ++o) sv[o] = sp[o] * zin;
    __shared__ float m[16][129];
#pragma unroll
    for (int o = 0; o < 16; ++o) m[o][b] = sv[o] * sv[o];
    __syncthreads();
    __shared__ float sn[16];
    if (b < 16) {
        float t = 0.f;
        for (int i = 0; i < 128; ++i) t += m[b][i];
        sn[b] = t;
    }
    __syncthreads();
#pragma unroll
    for (int o = 0; o < 16; ++o) {
        float scale = sqrtf(sn[o]) / (1.f + sn[o]);
        out[((size_t)b * 10 + c) * 16 + o] = sv[o] * scale;
    }
}

// ---------------- launch ----------------------------------------------------------------
extern "C" void kernel_launch(void* const* d_in, const int* in_sizes, int n_in,
                              void* d_out, int out_size, void* d_ws, size_t ws_size,
                              hipStream_t stream)
{
    (void)in_sizes; (void)n_in; (void)out_size; (void)ws_size;
    const float* inp = (const float*)d_in[0];
    const float* cw  = (const float*)d_in[1];
    const float* cb  = (const float*)d_in[2];
    const float* rw  = (const float*)d_in[3];
    float* out = (float*)d_out;

    // workspace layout (bytes), total ~94.8 MB:
    //   [0, 33.0M)   part f16 [14,4608,256]   (conv -> combine)
    //   [0, 47.2M)   pred f16 [10,128,1152,16] (aliases part; part dead after combine)
    //   [47.2M, ..)  x, a, sA, zA, sB, zB
    //   [58.0M, ..)  in_t (conv-time only), w_t (conv-time only)
    char* ws = (char*)d_ws;
    f16*   part = (f16*)(ws);                    // 33,030,144
    f16*   pred = (f16*)(ws);                    // 47,185,920 (alias)
    float* x    = (float*)(ws + 47185920);       //  4,718,592
    float* a    = (float*)(ws + 51904512);       //  5,898,240
    float* sA   = (float*)(ws + 57802752);       //     81,920
    float* zA   = (float*)(ws + 57884672);       //      5,120
    float* sB   = (float*)(ws + 57889792);       //     81,920
    float* zB   = (float*)(ws + 57971712);       //      5,120
    f16*   in_t = (f16*)(ws + 57976832);         // 26,214,400
    f16*   w_t  = (f16*)(ws + 84191232);         // 10,616,832 -> end 94,808,064

    transpose_input<<<dim3(128, 8, 13), dim3(32, 8), 0, stream>>>(inp, in_t);
    permute_w<<<256, 256, 0, stream>>>(cw, w_t);
    conv_mfma<<<dim3(36, 1, SPLITK), 256, 0, stream>>>(in_t, w_t, part);
    combine_squash<<<576, 256, 0, stream>>>(part, cb, x);

    hipMemsetAsync(sA, 0, 81920, stream);
    pred_s0<<<dim3(10, 36, 4), 256, 0, stream>>>(x, rw, pred, sA);   // pred + iter0 s

    route_f16<<<dim3(10, 128), 256, 0, stream>>>(pred, sA, nullptr, nullptr,
                                                 a, sB, zB);          // iter 1 (z0=1152)
    route_f16<<<dim3(10, 128), 256, 0, stream>>>(pred, sB, zB, a,
                                                 nullptr, sA, zA);    // iter 2
    squash_final<<<10, 128, 0, stream>>>(sA, zA, out);
}

// Round 2
// 246.083 us; speedup vs baseline: 1.1362x; 1.0192x over previous
//
#include <hip/hip_runtime.h>
#include <math.h>

typedef _Float16 f16;
typedef _Float16 f16x8 __attribute__((ext_vector_type(8)));
typedef float f32x4 __attribute__((ext_vector_type(4)));
typedef float f32x8 __attribute__((ext_vector_type(8)));

#define AS1 __attribute__((address_space(1)))
#define AS3 __attribute__((address_space(3)))

__device__ __forceinline__ void gld_lds16(const f16* g, f16* l) {
#if defined(__has_builtin) && __has_builtin(__builtin_amdgcn_global_load_lds)
    __builtin_amdgcn_global_load_lds((const AS1 void*)g, (AS3 void*)l, 16, 0, 0);
#else
    *(uint4*)l = *(const uint4*)g;
#endif
}

// ---------------- pre-pass 1: input [128,256,20,20] f32 -> [128,20,20,256] f16 ----------
__global__ __launch_bounds__(256) void transpose_input(
    const float* __restrict__ inp, f16* __restrict__ out)
{
    const int b = blockIdx.x, c0 = blockIdx.y * 32, p0 = blockIdx.z * 32;
    const int tx = threadIdx.x, ty = threadIdx.y;   // 32 x 8
    __shared__ float t[32][33];
#pragma unroll
    for (int j = 0; j < 4; ++j) {
        int c = ty + j * 8, p = p0 + tx;
        if (p < 400) t[c][tx] = inp[((size_t)b * 256 + c0 + c) * 400 + p];
    }
    __syncthreads();
#pragma unroll
    for (int j = 0; j < 4; ++j) {
        int p = p0 + ty + j * 8;
        if (p < 400) out[((size_t)b * 400 + p) * 256 + c0 + tx] = (f16)t[tx][ty + j * 8];
    }
}

// ---------------- pre-pass 2: conv_w [n=256][cin=256][p=81] f32 -> w_t[n][p*256+cin] f16 -
__global__ __launch_bounds__(256) void permute_w(
    const float* __restrict__ cw, f16* __restrict__ w_t)
{
    const int n = blockIdx.x, t = threadIdx.x;
    __shared__ f16 buf[81 * 258];
    const float* src = cw + (size_t)n * 20736;
    for (int i = t; i < 20736; i += 256) {
        int cin = i / 81, p = i - cin * 81;
        buf[p * 258 + cin] = (f16)src[i];
    }
    __syncthreads();
    f16* dst = w_t + (size_t)n * 20736;
    for (int j = t; j < 20736; j += 256) {
        int p = j >> 8, cin = j & 255;
        dst[j] = buf[p * 258 + cin];
    }
}

// ---------------- conv as implicit-im2col MFMA GEMM, 2-phase interleaved pipeline ------
// M=4608, N=256, K = 648 chunks of 32 f16 (ordered kh,kw,cin-quarter).
// Block tile 128x256, BK=32, 4 waves (2x2), wave tile 64x128 (4x8 frags of 16x16x32).
// THREE LDS buffers (72 KB -> 2 blocks/CU), prefetch depth 2, counted vmcnt(6).
// NEW (R2): each K-step is split into 2 phases of 16 MFMA following the m201 8-phase
// rhythm: {ds_read subtile ; issue 3 stage loads ; s_barrier ; lgkmcnt(0) ; setprio(1)
// 16 MFMA setprio(0) ; s_barrier}. ds_read latency hides under the barrier wait; the
// stage loads stay in flight across barriers (vmcnt never drains to 0 mid-loop).
// Safety: tile-t reads are issued after iter t-1 phase-B's vmcnt(6)+barrier (tile t
// resident for ALL waves); stage into buf[(t+2)%3] issues only after iter t-1's final
// barrier, by which point every wave has consumed (lgkmcnt(0)) its tile t-1 reads.
#define SPLITK 14
__global__ __launch_bounds__(256, 2) void conv_mfma(
    const f16* __restrict__ in_t,   // [128,20,20,256]
    const f16* __restrict__ w_t,    // [256,20736]
    f16* __restrict__ part)         // [14,4608,256] f16
{
    __shared__ f16 As[3][128 * 32];
    __shared__ f16 Bs[3][256 * 32];
    const int tid = threadIdx.x;
    const int lane = tid & 63, wave = tid >> 6;
    const int wm = wave >> 1, wn = wave & 1;

    // 504 blocks = 8 XCDs * 63: bijective chunk swizzle (same-kz blocks share an XCD L2)
    const int bid = blockIdx.x + 36 * blockIdx.z;
    const int wgid = (bid & 7) * 63 + (bid >> 3);
    const int m0 = (wgid % 36) * 128;
    const int kz = wgid / 36;

    // K-chunk range: 648 = 14*46 + 4 (first 4 splits take 47)
    const int kc0 = kz * 46 + (kz < 4 ? kz : 4);
    const int NT  = (kz < 4) ? 47 : 46;

    // staging source offsets (pre-swizzled global source, linear LDS dest)
    int srcA[2], srcB[4];
#pragma unroll
    for (int i = 0; i < 2; ++i) {
        int pairp = i * 32 + (tid >> 3);
        int chunk8 = (tid & 7) ^ (pairp & 7);
        int e = chunk8 >> 2, q4 = chunk8 & 3;
        int m = m0 + pairp * 2 + e;
        int b = m / 36, hw = m - b * 36;
        int ho = hw / 6, wo = hw - ho * 6;
        srcA[i] = ((b * 20 + 2 * ho) * 20 + 2 * wo) * 256 + q4 * 8;
    }
#pragma unroll
    for (int i = 0; i < 4; ++i) {
        int pairp = i * 32 + (tid >> 3);
        int chunk8 = (tid & 7) ^ (pairp & 7);
        int e = chunk8 >> 2, q4 = chunk8 & 3;
        int n = pairp * 2 + e;
        srcB[i] = n * 20736 + q4 * 8;
    }

    // fragment read offsets inside one tile buffer (swizzled, matches staging)
    const int row = lane & 15, quad = lane >> 4;
    int offA[4], offB[8];
#pragma unroll
    for (int mt = 0; mt < 4; ++mt) {
        int m = wm * 64 + mt * 16 + row;
        int ph8 = (((m & 1) << 2) + quad) ^ ((m >> 1) & 7);
        offA[mt] = (m >> 1) * 64 + ph8 * 8;
    }
#pragma unroll
    for (int nt = 0; nt < 8; ++nt) {
        int n = wn * 128 + nt * 16 + row;
        int ph8 = (((n & 1) << 2) + quad) ^ ((n >> 1) & 7);
        offB[nt] = (n >> 1) * 64 + ph8 * 8;
    }

    f32x4 acc[4][8] = {};

#define KOFFS(T) int kc = kc0 + (T); int pp = kc >> 3, cq = kc & 7;           \
    int kh = pp / 9, kw = pp - kh * 9;                                        \
    int koffA = (kh * 20 + kw) * 256 + cq * 32; int koffB = kc * 32;
#define STAGE1(T, BUF) do { KOFFS(T)                                          \
        gld_lds16(in_t + srcA[0] + koffA, &As[BUF][tid * 8]);                 \
        gld_lds16(in_t + srcA[1] + koffA, &As[BUF][2048 + tid * 8]);          \
        gld_lds16(w_t + srcB[0] + koffB, &Bs[BUF][tid * 8]);                  \
    } while (0)
#define STAGE2(T, BUF) do { KOFFS(T)                                          \
        gld_lds16(w_t + srcB[1] + koffB, &Bs[BUF][2048 + tid * 8]);           \
        gld_lds16(w_t + srcB[2] + koffB, &Bs[BUF][4096 + tid * 8]);           \
        gld_lds16(w_t + srcB[3] + koffB, &Bs[BUF][6144 + tid * 8]);           \
    } while (0)

    // prologue: 2 tiles in flight (12 loads/thread outstanding), wait tile 0 only
    STAGE1(0, 0); STAGE2(0, 0);
    STAGE1(1, 1); STAGE2(1, 1);
    asm volatile("s_waitcnt vmcnt(6)" ::: "memory");
    __builtin_amdgcn_s_barrier();

    int buf = 0;
    for (int t = 0; t < NT; ++t) {
        const f16* Ab = &As[buf][0];
        const f16* Bb = &Bs[buf][0];
        int bn = buf + 2; if (bn >= 3) bn -= 3;
        f16x8 af[4], bfr[8];

        // ---------------- phase A: af[0..3], bfr[0..3] -> acc[*][0..3] ----------------
#pragma unroll
        for (int mt = 0; mt < 4; ++mt) af[mt] = *(const f16x8*)(Ab + offA[mt]);
#pragma unroll
        for (int nt = 0; nt < 4; ++nt) bfr[nt] = *(const f16x8*)(Bb + offB[nt]);
        if (t + 2 < NT) STAGE1(t + 2, bn);
        __builtin_amdgcn_s_barrier();
        asm volatile("s_waitcnt lgkmcnt(0)" ::: "memory");
        __builtin_amdgcn_sched_barrier(0);
        __builtin_amdgcn_s_setprio(1);
#pragma unroll
        for (int mt = 0; mt < 4; ++mt)
#pragma unroll
            for (int nt = 0; nt < 4; ++nt)
                acc[mt][nt] = __builtin_amdgcn_mfma_f32_16x16x32_f16(
                    af[mt], bfr[nt], acc[mt][nt], 0, 0, 0);
        __builtin_amdgcn_s_setprio(0);
        __builtin_amdgcn_s_barrier();

        // ---------------- phase B: bfr[4..7] -> acc[*][4..7] --------------------------
#pragma unroll
        for (int nt = 4; nt < 8; ++nt) bfr[nt] = *(const f16x8*)(Bb + offB[nt]);
        if (t + 2 < NT) STAGE2(t + 2, bn);
        if (t + 2 < NT)
            asm volatile("s_waitcnt vmcnt(6)" ::: "memory");   // tile t+1 resident
        else if (t + 1 < NT)
            asm volatile("s_waitcnt vmcnt(0)" ::: "memory");   // drain only at tail
        __builtin_amdgcn_s_barrier();
        asm volatile("s_waitcnt lgkmcnt(0)" ::: "memory");
        __builtin_amdgcn_sched_barrier(0);
        __builtin_amdgcn_s_setprio(1);
#pragma unroll
        for (int mt = 0; mt < 4; ++mt)
#pragma unroll
            for (int nt = 4; nt < 8; ++nt)
                acc[mt][nt] = __builtin_amdgcn_mfma_f32_16x16x32_f16(
                    af[mt], bfr[nt], acc[mt][nt], 0, 0, 0);
        __builtin_amdgcn_s_setprio(0);
        __builtin_amdgcn_s_barrier();

        if (++buf == 3) buf = 0;
    }
#undef STAGE1
#undef STAGE2
#undef KOFFS

    // epilogue: f16 stores to partial buffer
    const int col = lane & 15, qr = (lane >> 4) * 4;
    f16* pb = part + (size_t)kz * 4608 * 256;
#pragma unroll
    for (int mt = 0; mt < 4; ++mt)
#pragma unroll
        for (int rg = 0; rg < 4; ++rg) {
            int m = m0 + wm * 64 + mt * 16 + qr + rg;
#pragma unroll
            for (int nt = 0; nt < 8; ++nt) {
                int n = wn * 128 + nt * 16 + col;
                pb[(size_t)m * 256 + n] = (f16)acc[mt][nt][rg];
            }
        }
}

// ---------------- split-K reduce + bias + capsule squash -> x[128,1152,8] ---------------
__global__ __launch_bounds__(256) void combine_squash(
    const f16* __restrict__ part, const float* __restrict__ bias,
    float* __restrict__ x)
{
    int idx = blockIdx.x * 256 + threadIdx.x;   // over 4608*32
    int m = idx >> 5, o = idx & 31;
    int b = m / 36, hw = m - b * 36;
    float val[8];
#pragma unroll
    for (int k = 0; k < 8; ++k) val[k] = bias[k * 32 + o];
#pragma unroll
    for (int s = 0; s < SPLITK; ++s) {
        const f16* p = part + ((size_t)s * 4608 + m) * 256 + o;
#pragma unroll
        for (int k = 0; k < 8; ++k) val[k] += (float)p[k * 32];
    }
    float sn = 0.f;
#pragma unroll
    for (int k = 0; k < 8; ++k) sn += val[k] * val[k];
    float scale = sqrtf(sn) / (1.f + sn);
    int r = o * 36 + hw;
    float* xp = x + ((size_t)b * 1152 + r) * 8;
#pragma unroll
    for (int k = 0; k < 8; ++k) xp[k] = val[k] * scale;
}

// ---------------- pred (f16) + fused routing-iter-0 s-accumulation ----------------------
// pred[c,b,r,o] = sum_k x[b,r,k]*rw[c,r,k,o]; also s0[c,b,o] += sum_r pred. s0 pre-zeroed.
__global__ __launch_bounds__(256) void pred_s0(
    const float* __restrict__ x, const float* __restrict__ rw,
    f16* __restrict__ pred, float* __restrict__ s0)
{
    const int c = blockIdx.x, r0 = blockIdx.y * 32, b0 = blockIdx.z * 32;
    const int tid = threadIdx.x;
    const int o = tid & 15, rp = tid >> 4;
    const int r = r0 + rp * 2;

    __shared__ float s_sh[32 * 16];
    s_sh[tid] = 0.f; s_sh[tid + 256] = 0.f;

    float W0[8], W1[8];
    const float* wb = rw + ((size_t)(c * 1152 + r) * 8) * 16 + o;
#pragma unroll
    for (int k = 0; k < 8; ++k) { W0[k] = wb[k * 16]; W1[k] = wb[128 + k * 16]; }
    __syncthreads();

    for (int bb = 0; bb < 32; ++bb) {
        const int b = b0 + bb;
        const float4* xp = (const float4*)(x + ((size_t)b * 1152 + r) * 8);
        float4 xa = xp[0], xb = xp[1], xc = xp[2], xd = xp[3];
        float p0 = xa.x * W0[0] + xa.y * W0[1] + xa.z * W0[2] + xa.w * W0[3]
                 + xb.x * W0[4] + xb.y * W0[5] + xb.z * W0[6] + xb.w * W0[7];
        float p1 = xc.x * W1[0] + xc.y * W1[1] + xc.z * W1[2] + xc.w * W1[3]
                 + xd.x * W1[4] + xd.y * W1[5] + xd.z * W1[6] + xd.w * W1[7];
        f16* pb = pred + ((size_t)(c * 128 + b) * 1152 + r) * 16 + o;
        pb[0]  = (f16)p0;
        pb[16] = (f16)p1;
        float ps = p0 + p1;
        ps += __shfl_xor(ps, 16);
        ps += __shfl_xor(ps, 32);
        if ((tid & 63) < 16) atomicAdd(&s_sh[bb * 16 + o], ps);
    }
    __syncthreads();
    for (int i = tid; i < 512; i += 256) {
        int bb = i >> 4, oo = i & 15;
        atomicAdd(&s0[((size_t)c * 128 + b0 + bb) * 16 + oo], s_sh[i]);
    }
}

// ---------------- routing iteration with inline batch-squash ----------------------------
__global__ __launch_bounds__(256) void route_f16(
    const f16* __restrict__ pred, const float* __restrict__ s_in,
    const float* __restrict__ z_in, const float* __restrict__ a_in,
    float* __restrict__ a_out, float* __restrict__ s_out, float* __restrict__ z_out)
{
    const int c = blockIdx.x, b = blockIdx.y, tid = threadIdx.x;
    const size_t base = (size_t)(c * 128 + b) * 1152;

    __shared__ float vs[16];
    __shared__ float mat[128][17];
    __shared__ float red[256][16];
    __shared__ float red2[16][16];
    __shared__ float zred[256];
    __shared__ float zpart[16];

    {   // inline squash(s_prev/z_prev, axis=batch) -> v_prev for this (c,b)
        if (tid < 128) {
            float zin = z_in ? 1.f / z_in[c * 128 + tid] : (1.f / 1152.f);
            const float* sp = s_in + (size_t)(c * 128 + tid) * 16;
#pragma unroll
            for (int o = 0; o < 16; ++o) mat[tid][o] = sp[o] * zin;
        }
        __syncthreads();
        if (tid < 16) {
            float sn = 0.f;
            for (int i = 0; i < 128; ++i) { float q = mat[i][tid]; sn += q * q; }
            vs[tid] = mat[b][tid] * sqrtf(sn) / (1.f + sn);
        }
        __syncthreads();
    }

    float sacc[16];
#pragma unroll
    for (int o = 0; o < 16; ++o) sacc[o] = 0.f;
    float zacc = 0.f;

    for (int r = tid; r < 1152; r += 256) {
        const f16x8* pp = (const f16x8*)(pred + (base + r) * 16);
        f32x8 q0 = __builtin_convertvector(pp[0], f32x8);
        f32x8 q1 = __builtin_convertvector(pp[1], f32x8);
        float contrib = 0.f;
#pragma unroll
        for (int j = 0; j < 8; ++j) contrib += q0[j] * vs[j] + q1[j] * vs[j + 8];
        float an = contrib + (a_in ? a_in[base + r] : 0.f);
        if (a_out) a_out[base + r] = an;
        float e = __expf(an);
#pragma unroll
        for (int j = 0; j < 8; ++j) { sacc[j] += e * q0[j]; sacc[j + 8] += e * q1[j]; }
        zacc += e;
    }

#pragma unroll
    for (int o = 0; o < 16; ++o) red[tid][o] = sacc[o];
    zred[tid] = zacc;
    __syncthreads();
    {
        const int o = tid & 15, seg = tid >> 4;
        float t = 0.f;
#pragma unroll
        for (int j = 0; j < 16; ++j) t += red[seg * 16 + j][o];
        red2[seg][o] = t;
        if (tid < 16) {
            float tz = 0.f;
#pragma unroll
            for (int j = 0; j < 16; ++j) tz += zred[tid * 16 + j];
            zpart[tid] = tz;
        }
    }
    __syncthreads();
    if (tid < 16) {
        float t = 0.f;
#pragma unroll
        for (int seg = 0; seg < 16; ++seg) t += red2[seg][tid];
        s_out[(size_t)(c * 128 + b) * 16 + tid] = t;
    } else if (tid == 16) {
        float tz = 0.f;
#pragma unroll
        for (int j = 0; j < 16; ++j) tz += zpart[j];
        z_out[c * 128 + b] = tz;
    }
}

// ---------------- final: v = squash(s/z, axis=batch) -> out[b,c,o] ----------------------
__global__ __launch_bounds__(128) void squash_final(
    const float* __restrict__ s, const float* __restrict__ z,
    float* __restrict__ out)
{
    const int c = blockIdx.x, b = threadIdx.x;   // 10 blocks, 128 threads
    float sv[16];
    const float* sp = s + ((size_t)c * 128 + b) * 16;
    float zin = 1.f / z[c * 128 + b];
#pragma unroll
    for (int o = 0; o < 16; ++o) sv[o] = sp[o] * zin;
    __shared__ float m[16][129];
#pragma unroll
    for (int o = 0; o < 16; ++o) m[o][b] = sv[o] * sv[o];
    __syncthreads();
    __shared__ float sn[16];
    if (b < 16) {
        float t = 0.f;
        for (int i = 0; i < 128; ++i) t += m[b][i];
        sn[b] = t;
    }
    __syncthreads();
#pragma unroll
    for (int o = 0; o < 16; ++o) {
        float scale = sqrtf(sn[o]) / (1.f + sn[o]);
        out[((size_t)b * 10 + c) * 16 + o] = sv[o] * scale;
    }
}

// ---------------- launch ----------------------------------------------------------------
extern "C" void kernel_launch(void* const* d_in, const int* in_sizes, int n_in,
                              void* d_out, int out_size, void* d_ws, size_t ws_size,
                              hipStream_t stream)
{
    (void)in_sizes; (void)n_in; (void)out_size; (void)ws_size;
    const float* inp = (const float*)d_in[0];
    const float* cw  = (const float*)d_in[1];
    const float* cb  = (const float*)d_in[2];
    const float* rw  = (const float*)d_in[3];
    float* out = (float*)d_out;

    // workspace layout (bytes), total ~94.8 MB:
    //   [0, 33.0M)   part f16 [14,4608,256]   (conv -> combine)
    //   [0, 47.2M)   pred f16 [10,128,1152,16] (aliases part; part dead after combine)
    //   [47.2M, ..)  x, a, sA, zA, sB, zB
    //   [58.0M, ..)  in_t (conv-time only), w_t (conv-time only)
    char* ws = (char*)d_ws;
    f16*   part = (f16*)(ws);                    // 33,030,144
    f16*   pred = (f16*)(ws);                    // 47,185,920 (alias)
    float* x    = (float*)(ws + 47185920);       //  4,718,592
    float* a    = (float*)(ws + 51904512);       //  5,898,240
    float* sA   = (float*)(ws + 57802752);       //     81,920
    float* zA   = (float*)(ws + 57884672);       //      5,120
    float* sB   = (float*)(ws + 57889792);       //     81,920
    float* zB   = (float*)(ws + 57971712);       //      5,120
    f16*   in_t = (f16*)(ws + 57976832);         // 26,214,400
    f16*   w_t  = (f16*)(ws + 84191232);         // 10,616,832 -> end 94,808,064

    transpose_input<<<dim3(128, 8, 13), dim3(32, 8), 0, stream>>>(inp, in_t);
    permute_w<<<256, 256, 0, stream>>>(cw, w_t);
    conv_mfma<<<dim3(36, 1, SPLITK), 256, 0, stream>>>(in_t, w_t, part);
    combine_squash<<<576, 256, 0, stream>>>(part, cb, x);

    hipMemsetAsync(sA, 0, 81920, stream);
    pred_s0<<<dim3(10, 36, 4), 256, 0, stream>>>(x, rw, pred, sA);   // pred + iter0 s

    route_f16<<<dim3(10, 128), 256, 0, stream>>>(pred, sA, nullptr, nullptr,
                                                 a, sB, zB);          // iter 1 (z0=1152)
    route_f16<<<dim3(10, 128), 256, 0, stream>>>(pred, sB, zB, a,
                                                 nullptr, sA, zA);    // iter 2
    squash_final<<<10, 128, 0, stream>>>(sA, zA, out);
}